// Round 7
// baseline (995.331 us; speedup 1.0000x reference)
//
#include <hip/hip_runtime.h>
#include <hip/hip_bf16.h>

// 2-layer LSTM (H=20) + FC(20->1), B=4096, T=512, D_in=1.
//
// Mapping: block = 256 threads = 4 waves, GPB=3 batch elements.
// Wave w owns gate w (torch order i,f,g,o); lanes [20g,20g+19] = group g
// (batch b = 3*blk + g); lane j owns hidden unit j -> gate row w*20+j.
//
// Round-6 change: rounds 1-5 proved the allocator ALWAYS parks the 60-float
// weight set in AGPRs (VGPR_Count 60-96 regardless of launch bounds; hidden
// AGPRs confirmed by occupancy arithmetic: 10.5 waves/CU = 2048/(60+~75)).
// Each implicit AGPR use cost ~3-5 issue slots (accvgpr traffic + reload
// address math): measured 650 busy-cyc/wave-step vs ~210 useful.
// Fix: make AGPR residence EXPLICIT and the per-use cost exactly 2 instr:
//   - pin each weight with asm("+a") once (AGPR-resident, opaque -> the
//     compiler cannot reload or rematerialize it),
//   - at each use, one explicit v_accvgpr_read_b32 into a temp, then a
//     plain fmaf. Reads from different chains interleave; fmafs schedule
//     freely around them.
// Also: h-broadcast rows padded 24 -> 28 floats so the 3 group rows hit
// banks {0,28,24} instead of all bank 0 (round-5 SQ_LDS_BANK_CONFLICT).
//
// (Round 6 submission never executed: GPUAcquisitionTimeout. Resubmitted
// unchanged in round 7.)

namespace {
constexpr int H_  = 20;
constexpr int T_  = 512;
constexpr int B_  = 4096;
constexpr int GPB = 3;    // batch elements (groups) per block

__device__ __forceinline__ float sigm(float v) {
    return 1.0f / (1.0f + __expf(-v));
}
__device__ __forceinline__ float tanh_fast(float v) {
    // tanh(v) = 1 - 2/(1+e^{2v}); saturates correctly for large |v|
    return 1.0f - 2.0f / (1.0f + __expf(2.0f * v));
}
// Explicit AGPR -> VGPR read of an AGPR-pinned weight (1 instruction).
__device__ __forceinline__ float awt(const float& w) {
    float t;
    asm volatile("v_accvgpr_read_b32 %0, %1" : "=v"(t) : "a"(w));
    return t;
}
} // namespace

__global__ __launch_bounds__(256, 3) void lstm2_fc_kernel(
    const float* __restrict__ x,
    const float* __restrict__ Wih0, const float* __restrict__ Whh0,
    const float* __restrict__ bih0, const float* __restrict__ bhh0,
    const float* __restrict__ Wih1, const float* __restrict__ Whh1,
    const float* __restrict__ bih1, const float* __restrict__ bhh1,
    const float* __restrict__ fcW,  const float* __restrict__ fcb,
    float* __restrict__ out)
{
    const int tid  = threadIdx.x;
    const int w_s  = __builtin_amdgcn_readfirstlane(tid >> 6); // gate 0..3 (SGPR)
    const int lane = tid & 63;
    const int g    = lane / H_;           // group 0..2 active, 3 = pad
    const int j    = lane - g * H_;       // hidden unit 0..19
    const int b    = blockIdx.x * GPB + g;
    const bool st  = (g < GPB) && (b < B_);
    const int  gx  = (g < GPB) ? g : (GPB - 1);

    __shared__ float xs[GPB][T_ + 1];                // staged x (pad slot 512)
    __shared__ float act0[4][64];                    // [gate][lane]
    __shared__ float act1[4][64];
    __shared__ __align__(16) float h0s[4][4][28];    // [wave][group][unit pad28]
    __shared__ __align__(16) float h1s[4][4][28];    // 28: groups hit banks 0/28/24

    // ---- stage x rows for this block's 3 batch elements (coalesced) ----
    {
        const int base_b = blockIdx.x * GPB;
        for (int idx = tid; idx < GPB * T_; idx += 256) {
            const int gg  = idx >> 9;           // /512
            const int tt  = idx & (T_ - 1);     // %512
            int row = base_b + gg; if (row >= B_) row = B_ - 1;
            xs[gg][tt] = x[(size_t)row * T_ + tt];
        }
    }

    // ---- lane-private weights: gate row r = w_s*20 + j ----
    const int r = w_s * H_ + j;
    float w0x   = Wih0[r];                           // Wih0 is [80,1]
    float bias0 = bih0[r] + bhh0[r];
    float bias1 = bih1[r] + bhh1[r];
    float w0h[H_], w1i[H_], w1h[H_];
    #pragma unroll
    for (int k = 0; k < H_; ++k) {
        w0h[k] = Whh0[r * H_ + k];
        w1i[k] = Wih1[r * H_ + k];
        w1h[k] = Whh1[r * H_ + k];
    }
    // Pin the 3 per-step scalars in arch VGPRs (tiny, used once/step)...
    asm volatile("" : "+v"(w0x), "+v"(bias0), "+v"(bias1));
    // ...and the 60 dot-product weights in AGPRs (opaque: no reload/remat).
    #pragma unroll
    for (int k = 0; k < H_; ++k) {
        asm volatile("" : "+a"(w0h[k]), "+a"(w1i[k]), "+a"(w1h[k]));
    }

    // ---- state (replicated across waves, bitwise-consistent) ----
    float h0r[H_], h1r[H_];
    #pragma unroll
    for (int k = 0; k < H_; ++k) { h0r[k] = 0.0f; h1r[k] = 0.0f; }
    float c0 = 0.0f, c1 = 0.0f;

    float* myAct0 = &act0[w_s][lane];
    float* myAct1 = &act1[w_s][lane];
    const float4* h0row = reinterpret_cast<const float4*>(&h0s[w_s][g][0]);
    const float4* h1row = reinterpret_cast<const float4*>(&h1s[w_s][g][0]);
    const float*  xrow  = &xs[gx][0];

    __syncthreads();                                 // xs ready
    float xv = xrow[0];

    #pragma unroll 1
    for (int t = 0; t < T_; ++t) {
        // ============ layer 0: own gate row (21 MACs, 4 chains) ============
        float s0 = fmaf(w0x, xv, bias0);
        float s1 = 0.0f, s2 = 0.0f, s3 = 0.0f;
        #pragma unroll
        for (int k = 0; k < H_; k += 4) {
            s0 = fmaf(awt(w0h[k + 0]), h0r[k + 0], s0);
            s1 = fmaf(awt(w0h[k + 1]), h0r[k + 1], s1);
            s2 = fmaf(awt(w0h[k + 2]), h0r[k + 2], s2);
            s3 = fmaf(awt(w0h[k + 3]), h0r[k + 3], s3);
        }
        const float gate0 = (s0 + s1) + (s2 + s3);
        float a0;
        if (w_s == 2) a0 = tanh_fast(gate0); else a0 = sigm(gate0);
        *myAct0 = a0;
        const float xnext = xrow[t + 1];   // t=511 reads pad slot; never used
        __syncthreads();                                   // BAR 1
        const float i0 = act0[0][lane];
        const float f0 = act0[1][lane];
        const float z0 = act0[2][lane];
        const float o0 = act0[3][lane];
        c0 = fmaf(f0, c0, i0 * z0);
        const float h0n = o0 * tanh_fast(c0);
        h0s[w_s][g][j] = h0n;                              // wave-private row

        // broadcast readback (intra-wave RAW, no barrier needed)
        #pragma unroll
        for (int c4 = 0; c4 < 5; ++c4) {
            const float4 v = h0row[c4];
            h0r[c4 * 4 + 0] = v.x; h0r[c4 * 4 + 1] = v.y;
            h0r[c4 * 4 + 2] = v.z; h0r[c4 * 4 + 3] = v.w;
        }

        // ============ layer 1: own gate row (40 MACs, 4 chains) ============
        float u0 = bias1, u1 = 0.0f, u2 = 0.0f, u3 = 0.0f;
        #pragma unroll
        for (int k = 0; k < H_; k += 2) {
            u0 = fmaf(awt(w1i[k + 0]), h0r[k + 0], u0);
            u1 = fmaf(awt(w1i[k + 1]), h0r[k + 1], u1);
            u2 = fmaf(awt(w1h[k + 0]), h1r[k + 0], u2);
            u3 = fmaf(awt(w1h[k + 1]), h1r[k + 1], u3);
        }
        const float gate1 = (u0 + u1) + (u2 + u3);
        float a1;
        if (w_s == 2) a1 = tanh_fast(gate1); else a1 = sigm(gate1);
        *myAct1 = a1;
        __syncthreads();                                   // BAR 2
        const float i1 = act1[0][lane];
        const float f1 = act1[1][lane];
        const float z1 = act1[2][lane];
        const float o1 = act1[3][lane];
        c1 = fmaf(f1, c1, i1 * z1);
        const float h1n = o1 * tanh_fast(c1);
        h1s[w_s][g][j] = h1n;                              // wave-private row

        #pragma unroll
        for (int c4 = 0; c4 < 5; ++c4) {
            const float4 v = h1row[c4];
            h1r[c4 * 4 + 0] = v.x; h1r[c4 * 4 + 1] = v.y;
            h1r[c4 * 4 + 2] = v.z; h1r[c4 * 4 + 3] = v.w;
        }

        xv = xnext;
    }

    // ================= FC epilogue =================
    if (w_s == 0 && st && j == 0) {
        float acc = fcb[0];
        #pragma unroll
        for (int k = 0; k < H_; ++k) acc = fmaf(fcW[k], h1r[k], acc);
        out[b] = acc;
    }
}

extern "C" void kernel_launch(void* const* d_in, const int* in_sizes, int n_in,
                              void* d_out, int out_size, void* d_ws, size_t ws_size,
                              hipStream_t stream) {
    const float* x    = (const float*)d_in[0];
    const float* Wih0 = (const float*)d_in[1];
    const float* Whh0 = (const float*)d_in[2];
    const float* bih0 = (const float*)d_in[3];
    const float* bhh0 = (const float*)d_in[4];
    const float* Wih1 = (const float*)d_in[5];
    const float* Whh1 = (const float*)d_in[6];
    const float* bih1 = (const float*)d_in[7];
    const float* bhh1 = (const float*)d_in[8];
    const float* fcW  = (const float*)d_in[9];
    const float* fcb  = (const float*)d_in[10];
    float* out = (float*)d_out;

    const int grid = (B_ + GPB - 1) / GPB;   // 1366 blocks x 4 waves
    lstm2_fc_kernel<<<dim3(grid), dim3(256), 0, stream>>>(
        x, Wih0, Whh0, bih0, bhh0, Wih1, Whh1, bih1, bhh1, fcW, fcb, out);
}